// Round 1
// baseline (175.559 us; speedup 1.0000x reference)
//
#include <hip/hip_runtime.h>

#define CC 512
#define NN 1024
#define NB 8
#define NH 8
#define HD 64

typedef __attribute__((ext_vector_type(8))) short s16x8;
typedef __attribute__((ext_vector_type(4))) short s16x4;
typedef __attribute__((ext_vector_type(4))) float f32x4;

__device__ __forceinline__ short f2bf(float f){
  union { float f; unsigned u; } v; v.f = f;
  unsigned r = v.u + 0x7fffu + ((v.u >> 16) & 1u);
  return (short)(r >> 16);
}

__device__ __forceinline__ void gload16(const void* g, void* l){
  __builtin_amdgcn_global_load_lds((const __attribute__((address_space(1))) void*)g,
                                   (__attribute__((address_space(3))) void*)l, 16, 0, 0);
}

// ---------------- weight fp32 -> bf16 ----------------
__global__ __launch_bounds__(256) void wcvt(const float* __restrict__ w0, const float* __restrict__ w1,
    const float* __restrict__ w2, const float* __restrict__ w3, short* __restrict__ wbf){
  const int i = blockIdx.x*256 + threadIdx.x;          // 262144 threads, 4 elems each
  const int sel = i >> 16;
  const int off = (i & 65535) << 2;
  const float* src = (sel==0) ? w0 : (sel==1) ? w1 : (sel==2) ? w2 : w3;
  const float4 v = *reinterpret_cast<const float4*>(src + off);
  s16x4 o;
  o[0] = f2bf(v.x); o[1] = f2bf(v.y); o[2] = f2bf(v.z); o[3] = f2bf(v.w);
  *reinterpret_cast<s16x4*>(wbf + (size_t)sel*262144 + off) = o;
}

// ---------------- GroupNorm -> xn_t (b, n, c) bf16 ----------------
__global__ __launch_bounds__(256) void gn_kernel(const float* __restrict__ x,
    const float* __restrict__ gsc, const float* __restrict__ gbi, short* __restrict__ xnt){
  const int b = blockIdx.x >> 5;
  const int g = blockIdx.x & 31;
  const int t = threadIdx.x;
  const float* base = x + ((size_t)b*CC + g*16)*NN;
  float4 vals[16];
  float s = 0.f, s2 = 0.f;
  #pragma unroll
  for (int k = 0; k < 16; ++k){
    float4 v = *reinterpret_cast<const float4*>(base + k*NN + t*4);
    vals[k] = v;
    s  += v.x + v.y + v.z + v.w;
    s2 += v.x*v.x + v.y*v.y + v.z*v.z + v.w*v.w;
  }
  #pragma unroll
  for (int m = 1; m < 64; m <<= 1){ s += __shfl_xor(s, m); s2 += __shfl_xor(s2, m); }
  __shared__ float rs[4], rs2[4];
  const int wid = t >> 6, lane = t & 63;
  if (lane == 0){ rs[wid] = s; rs2[wid] = s2; }
  __syncthreads();
  s  = rs[0] + rs[1] + rs[2] + rs[3];
  s2 = rs2[0] + rs2[1] + rs2[2] + rs2[3];
  const float mean = s * (1.f/16384.f);
  const float inv = rsqrtf(s2 * (1.f/16384.f) - mean*mean + 1e-5f);
  float scl[16], off[16];
  #pragma unroll
  for (int k = 0; k < 16; ++k){
    const float sc = gsc[g*16 + k] * inv;
    scl[k] = sc;
    off[k] = gbi[g*16 + k] - mean * sc;
  }
  // thread t holds all 16 channels for n = 4t..4t+3 -> transpose is free
  short* obase = xnt + ((size_t)b*NN + t*4)*CC + g*16;
  #pragma unroll
  for (int i = 0; i < 4; ++i){
    s16x8 lo, hi;
    #pragma unroll
    for (int k = 0; k < 8; ++k){
      float v = (i==0) ? vals[k].x : (i==1) ? vals[k].y : (i==2) ? vals[k].z : vals[k].w;
      lo[k] = f2bf(v * scl[k] + off[k]);
    }
    #pragma unroll
    for (int k = 0; k < 8; ++k){
      float v = (i==0) ? vals[k+8].x : (i==1) ? vals[k+8].y : (i==2) ? vals[k+8].z : vals[k+8].w;
      hi[k] = f2bf(v * scl[k+8] + off[k+8]);
    }
    *reinterpret_cast<s16x8*>(obase + (size_t)i*CC)     = lo;
    *reinterpret_cast<s16x8*>(obase + (size_t)i*CC + 8) = hi;
  }
}

// ---------------- GEMM: Y[o][n] = sum_c W[o][c] * Bmat[n][c] (+bias, epilogues) ----------------
// MODE 0: z=0 -> q_t (b,h,n,c)*0.125; z=1 -> k_t (b,h,n,c); z=2 -> v (b,c,n)
// MODE 1: out f32 (b,c,n) = acc + bias + residual
template<int MODE>
__global__ __launch_bounds__(256) void gemm_kernel(
    const short* __restrict__ Wb, const short* __restrict__ Bmat,
    const float* __restrict__ bias0, const float* __restrict__ bias1, const float* __restrict__ bias2,
    const float* __restrict__ resid,
    short* __restrict__ qt, short* __restrict__ kt2, short* __restrict__ vo,
    float* __restrict__ outp)
{
  const int tile = blockIdx.x;
  const int batch = blockIdx.y;
  const int z = blockIdx.z;
  const int mt = tile >> 3, nt = tile & 7;
  const int tid = threadIdx.x;
  const int lane = tid & 63, wid = tid >> 6;
  const int wm = wid >> 1, wn = wid & 1;

  __shared__ short As[128*64];
  __shared__ short Bs[128*64];

  const short* Wz = Wb + (size_t)(MODE == 0 ? z : 3) * 262144;
  const short* Brow = Bmat + ((size_t)batch*NN + nt*128)*CC;

  const f32x4 fzero = {0.f, 0.f, 0.f, 0.f};
  f32x4 acc[4][4];
  #pragma unroll
  for (int i = 0; i < 4; ++i)
  #pragma unroll
  for (int j = 0; j < 4; ++j)
    acc[i][j] = fzero;

  for (int kk = 0; kk < 8; ++kk){
    __syncthreads();
    #pragma unroll
    for (int j = 0; j < 4; ++j){
      const int id = tid + 256*j;
      const int row = id >> 3, ch = id & 7;
      const int gch = ch ^ (row & 7);              // pre-swizzled source, linear LDS dest
      gload16(Wz   + (size_t)(mt*128 + row)*CC + kk*64 + gch*8, As + (wid*64 + 256*j)*8);
      gload16(Brow + (size_t)row*CC          + kk*64 + gch*8, Bs + (wid*64 + 256*j)*8);
    }
    __syncthreads();
    #pragma unroll
    for (int ks = 0; ks < 2; ++ks){
      s16x8 a[4], b[4];
      #pragma unroll
      for (int mi = 0; mi < 4; ++mi){
        const int row = wm*64 + mi*16 + (lane & 15);
        const int ch = (ks*4 + (lane >> 4)) ^ (row & 7);
        a[mi] = *reinterpret_cast<const s16x8*>(&As[row*64 + ch*8]);
      }
      #pragma unroll
      for (int ni = 0; ni < 4; ++ni){
        const int row = wn*64 + ni*16 + (lane & 15);
        const int ch = (ks*4 + (lane >> 4)) ^ (row & 7);
        b[ni] = *reinterpret_cast<const s16x8*>(&Bs[row*64 + ch*8]);
      }
      #pragma unroll
      for (int mi = 0; mi < 4; ++mi)
      #pragma unroll
      for (int ni = 0; ni < 4; ++ni)
        acc[mi][ni] = __builtin_amdgcn_mfma_f32_16x16x32_bf16(a[mi], b[ni], acc[mi][ni], 0, 0, 0);
    }
  }

  const int obase = mt*128 + wm*64;
  const int nbase = nt*128 + wn*64;
  if (MODE == 0){
    if (z < 2){
      const float* bias = (z == 0) ? bias0 : bias1;
      short* dst = (z == 0) ? qt : kt2;
      const float qs = (z == 0) ? 0.125f : 1.0f;
      const int head = mt*2 + wm;                  // wave's 64 o-rows = one head
      const size_t hb = ((size_t)batch*NH + head)*NN;
      #pragma unroll
      for (int mi = 0; mi < 4; ++mi){
        float bv4[4];
        #pragma unroll
        for (int r = 0; r < 4; ++r) bv4[r] = bias[obase + mi*16 + (lane>>4)*4 + r];
        const int c0 = mi*16 + (lane>>4)*4;
        #pragma unroll
        for (int ni = 0; ni < 4; ++ni){
          const int n = nbase + ni*16 + (lane & 15);
          s16x4 pk;
          #pragma unroll
          for (int r = 0; r < 4; ++r) pk[r] = f2bf((acc[mi][ni][r] + bv4[r]) * qs);
          *reinterpret_cast<s16x4*>(dst + (hb + n)*HD + c0) = pk;
        }
      }
    } else {
      #pragma unroll
      for (int mi = 0; mi < 4; ++mi){
        float bv4[4];
        #pragma unroll
        for (int r = 0; r < 4; ++r) bv4[r] = bias2[obase + mi*16 + (lane>>4)*4 + r];
        #pragma unroll
        for (int ni = 0; ni < 4; ++ni){
          const int n = nbase + ni*16 + (lane & 15);
          #pragma unroll
          for (int r = 0; r < 4; ++r){
            const int o = obase + mi*16 + (lane>>4)*4 + r;
            vo[((size_t)batch*CC + o)*NN + n] = f2bf(acc[mi][ni][r] + bv4[r]);
          }
        }
      }
    }
  } else {
    #pragma unroll
    for (int mi = 0; mi < 4; ++mi){
      float bv4[4];
      #pragma unroll
      for (int r = 0; r < 4; ++r) bv4[r] = bias0[obase + mi*16 + (lane>>4)*4 + r];
      #pragma unroll
      for (int ni = 0; ni < 4; ++ni){
        const int n = nbase + ni*16 + (lane & 15);
        #pragma unroll
        for (int r = 0; r < 4; ++r){
          const int o = obase + mi*16 + (lane>>4)*4 + r;
          const size_t idx = ((size_t)batch*CC + o)*NN + n;
          outp[idx] = acc[mi][ni][r] + bv4[r] + resid[idx];
        }
      }
    }
  }
}

// ---------------- flash attention per (b, h, 64-query tile) ----------------
__global__ __launch_bounds__(256) void attn_kernel(
    const short* __restrict__ qt, const short* __restrict__ ktp, const short* __restrict__ vp,
    short* __restrict__ ot)
{
  const int qtile = blockIdx.x;
  const int head = blockIdx.y;
  const int batch = blockIdx.z;
  const int tid = threadIdx.x, lane = tid & 63, wid = tid >> 6;
  const size_t bh = (size_t)batch*NH + head;

  __shared__ short P[4][16*64];                    // per-wave P tile (swizzled)
  short* Pw = P[wid];

  const int nq0 = qtile*64 + wid*16;               // each wave owns 16 queries
  s16x8 qf[2];
  #pragma unroll
  for (int ks = 0; ks < 2; ++ks)
    qf[ks] = *reinterpret_cast<const s16x8*>(qt + (bh*NN + nq0 + (lane & 15))*HD + ks*32 + (lane>>4)*8);

  float mrow[4], lrow[4];
  #pragma unroll
  for (int r = 0; r < 4; ++r){ mrow[r] = -1e30f; lrow[r] = 0.f; }
  const f32x4 fzero = {0.f, 0.f, 0.f, 0.f};
  f32x4 of[4];
  #pragma unroll
  for (int ci = 0; ci < 4; ++ci) of[ci] = fzero;

  const short* Kb = ktp + bh*NN*HD;
  const short* Vb = vp + ((size_t)batch*CC + head*HD)*NN;

  for (int it = 0; it < 16; ++it){
    const int m0 = it*64;
    f32x4 sf[4];
    #pragma unroll
    for (int mt = 0; mt < 4; ++mt) sf[mt] = fzero;
    #pragma unroll
    for (int ks = 0; ks < 2; ++ks){
      #pragma unroll
      for (int mt = 0; mt < 4; ++mt){
        const s16x8 kf = *reinterpret_cast<const s16x8*>(
            Kb + (size_t)(m0 + mt*16 + (lane & 15))*HD + ks*32 + (lane>>4)*8);
        sf[mt] = __builtin_amdgcn_mfma_f32_16x16x32_bf16(qf[ks], kf, sf[mt], 0, 0, 0);
      }
    }
    // online softmax: rows nq=(lane>>4)*4+r, cols m = mt*16 + (lane&15)
    float pe[4][4];
    float scf[4];
    #pragma unroll
    for (int r = 0; r < 4; ++r){
      float x = fmaxf(fmaxf(sf[0][r], sf[1][r]), fmaxf(sf[2][r], sf[3][r]));
      x = fmaxf(x, __shfl_xor(x, 1));
      x = fmaxf(x, __shfl_xor(x, 2));
      x = fmaxf(x, __shfl_xor(x, 4));
      x = fmaxf(x, __shfl_xor(x, 8));
      const float mn = fmaxf(mrow[r], x);
      scf[r] = __expf(mrow[r] - mn);
      mrow[r] = mn;
      float rsum = 0.f;
      #pragma unroll
      for (int mt = 0; mt < 4; ++mt){
        const float e = __expf(sf[mt][r] - mn);
        pe[mt][r] = e;
        rsum += e;
      }
      rsum += __shfl_xor(rsum, 1);
      rsum += __shfl_xor(rsum, 2);
      rsum += __shfl_xor(rsum, 4);
      rsum += __shfl_xor(rsum, 8);
      lrow[r] = lrow[r]*scf[r] + rsum;
    }
    // P -> LDS (bf16, XOR-swizzled 8-elem chunks)
    #pragma unroll
    for (int mt = 0; mt < 4; ++mt){
      const int m = mt*16 + (lane & 15);
      const int mh = m >> 3, ml = m & 7;
      #pragma unroll
      for (int r = 0; r < 4; ++r){
        const int nq = (lane>>4)*4 + r;
        Pw[nq*64 + ((mh ^ (nq & 7)) << 3) + ml] = f2bf(pe[mt][r]);
      }
    }
    // broadcast rescale factor to O-frag cols (col = lane&15)
    const int srcl = ((lane & 15) >> 2) << 4;
    const float f0 = __shfl(scf[0], srcl);
    const float f1 = __shfl(scf[1], srcl);
    const float f2 = __shfl(scf[2], srcl);
    const float f3 = __shfl(scf[3], srcl);
    const int rr = lane & 3;
    const float fac = (rr==0) ? f0 : (rr==1) ? f1 : (rr==2) ? f2 : f3;
    #pragma unroll
    for (int ci = 0; ci < 4; ++ci)
      #pragma unroll
      for (int r = 0; r < 4; ++r)
        of[ci][r] *= fac;
    // O += V * P^T
    #pragma unroll
    for (int ks = 0; ks < 2; ++ks){
      const int ch = (ks*4 + (lane>>4)) ^ (lane & 7);
      const s16x8 pf = *reinterpret_cast<const s16x8*>(&Pw[(lane & 15)*64 + ch*8]);
      #pragma unroll
      for (int ci = 0; ci < 4; ++ci){
        const s16x8 vf = *reinterpret_cast<const s16x8*>(
            Vb + (size_t)(ci*16 + (lane & 15))*NN + m0 + ks*32 + (lane>>4)*8);
        of[ci] = __builtin_amdgcn_mfma_f32_16x16x32_bf16(vf, pf, of[ci], 0, 0, 0);
      }
    }
  }
  // normalize and store (b, n, c) bf16
  const int srcl = ((lane & 15) >> 2) << 4;
  const float l0 = __shfl(lrow[0], srcl);
  const float l1 = __shfl(lrow[1], srcl);
  const float l2 = __shfl(lrow[2], srcl);
  const float l3 = __shfl(lrow[3], srcl);
  const int rr = lane & 3;
  const float lv = (rr==0) ? l0 : (rr==1) ? l1 : (rr==2) ? l2 : l3;
  const float invl = 1.f / lv;
  const int n = nq0 + (lane & 15);
  #pragma unroll
  for (int ci = 0; ci < 4; ++ci){
    s16x4 pk;
    #pragma unroll
    for (int r = 0; r < 4; ++r) pk[r] = f2bf(of[ci][r] * invl);
    *reinterpret_cast<s16x4*>(ot + ((size_t)batch*NN + n)*CC + head*HD + ci*16 + (lane>>4)*4) = pk;
  }
}

extern "C" void kernel_launch(void* const* d_in, const int* in_sizes, int n_in,
                              void* d_out, int out_size, void* d_ws, size_t ws_size,
                              hipStream_t stream) {
  const float* x   = (const float*)d_in[0];
  const float* gsc = (const float*)d_in[1];
  const float* gbi = (const float*)d_in[2];
  const float* wq  = (const float*)d_in[3];
  const float* bq  = (const float*)d_in[4];
  const float* wk  = (const float*)d_in[5];
  const float* bk  = (const float*)d_in[6];
  const float* wv  = (const float*)d_in[7];
  const float* bv  = (const float*)d_in[8];
  const float* wp  = (const float*)d_in[9];
  const float* bp  = (const float*)d_in[10];
  float* out = (float*)d_out;

  char* ws = (char*)d_ws;
  short* wbf = (short*)(ws);                 // 2 MiB: wq,wk,wv,wp bf16
  short* xnt = (short*)(ws + (2u<<20));      // 8 MiB: (b,n,c) bf16
  short* qt  = (short*)(ws + (10u<<20));     // 8 MiB: (b,h,n,c) bf16, pre-scaled by 1/8
  short* kt  = (short*)(ws + (18u<<20));     // 8 MiB: (b,h,n,c) bf16
  short* v   = (short*)(ws + (26u<<20));     // 8 MiB: (b,c,n) bf16
  short* aot = (short*)(ws + (34u<<20));     // 8 MiB: (b,n,c) bf16

  wcvt<<<1024, 256, 0, stream>>>(wq, wk, wv, wp, wbf);
  gn_kernel<<<256, 256, 0, stream>>>(x, gsc, gbi, xnt);
  gemm_kernel<0><<<dim3(32, 8, 3), 256, 0, stream>>>(wbf, xnt, bq, bk, bv, nullptr,
                                                     qt, kt, v, nullptr);
  attn_kernel<<<dim3(16, 8, 8), 256, 0, stream>>>(qt, kt, v, aot);
  gemm_kernel<1><<<dim3(32, 8, 1), 256, 0, stream>>>(wbf, aot, bp, nullptr, nullptr, x,
                                                     nullptr, nullptr, nullptr, out);
}

// Round 2
// 121.263 us; speedup vs baseline: 1.4478x; 1.4478x over previous
//
#include <hip/hip_runtime.h>

#define CC 512
#define NN 1024
#define NB 8
#define NH 8
#define HD 64

typedef __attribute__((ext_vector_type(8))) short s16x8;
typedef __attribute__((ext_vector_type(4))) short s16x4;
typedef __attribute__((ext_vector_type(4))) float f32x4;
typedef __attribute__((ext_vector_type(16))) float f32x16;

__device__ __forceinline__ short f2bf(float f){
  union { float f; unsigned u; } v; v.f = f;
  unsigned r = v.u + 0x7fffu + ((v.u >> 16) & 1u);
  return (short)(r >> 16);
}

__device__ __forceinline__ unsigned cvtpk(float lo, float hi){
  unsigned r;
  asm("v_cvt_pk_bf16_f32 %0, %1, %2" : "=v"(r) : "v"(lo), "v"(hi));
  return r;
}

__device__ __forceinline__ void gload16(const void* g, void* l){
  __builtin_amdgcn_global_load_lds((const __attribute__((address_space(1))) void*)g,
                                   (__attribute__((address_space(3))) void*)l, 16, 0, 0);
}

// ---------------- weight fp32 -> bf16 ----------------
__global__ __launch_bounds__(256) void wcvt(const float* __restrict__ w0, const float* __restrict__ w1,
    const float* __restrict__ w2, const float* __restrict__ w3, short* __restrict__ wbf){
  const int i = blockIdx.x*256 + threadIdx.x;
  const int sel = i >> 16;
  const int off = (i & 65535) << 2;
  const float* src = (sel==0) ? w0 : (sel==1) ? w1 : (sel==2) ? w2 : w3;
  const float4 v = *reinterpret_cast<const float4*>(src + off);
  s16x4 o;
  o[0] = f2bf(v.x); o[1] = f2bf(v.y); o[2] = f2bf(v.z); o[3] = f2bf(v.w);
  *reinterpret_cast<s16x4*>(wbf + (size_t)sel*262144 + off) = o;
}

// ---------------- GroupNorm -> xn_t (b, n, c) bf16 ----------------
__global__ __launch_bounds__(256) void gn_kernel(const float* __restrict__ x,
    const float* __restrict__ gsc, const float* __restrict__ gbi, short* __restrict__ xnt){
  const int b = blockIdx.x >> 5;
  const int g = blockIdx.x & 31;
  const int t = threadIdx.x;
  const float* base = x + ((size_t)b*CC + g*16)*NN;
  float4 vals[16];
  float s = 0.f, s2 = 0.f;
  #pragma unroll
  for (int k = 0; k < 16; ++k){
    float4 v = *reinterpret_cast<const float4*>(base + k*NN + t*4);
    vals[k] = v;
    s  += v.x + v.y + v.z + v.w;
    s2 += v.x*v.x + v.y*v.y + v.z*v.z + v.w*v.w;
  }
  #pragma unroll
  for (int m = 1; m < 64; m <<= 1){ s += __shfl_xor(s, m); s2 += __shfl_xor(s2, m); }
  __shared__ float rs[4], rs2[4];
  const int wid = t >> 6, lane = t & 63;
  if (lane == 0){ rs[wid] = s; rs2[wid] = s2; }
  __syncthreads();
  s  = rs[0] + rs[1] + rs[2] + rs[3];
  s2 = rs2[0] + rs2[1] + rs2[2] + rs2[3];
  const float mean = s * (1.f/16384.f);
  const float inv = rsqrtf(s2 * (1.f/16384.f) - mean*mean + 1e-5f);
  float scl[16], off[16];
  #pragma unroll
  for (int k = 0; k < 16; ++k){
    const float sc = gsc[g*16 + k] * inv;
    scl[k] = sc;
    off[k] = gbi[g*16 + k] - mean * sc;
  }
  short* obase = xnt + ((size_t)b*NN + t*4)*CC + g*16;
  #pragma unroll
  for (int i = 0; i < 4; ++i){
    s16x8 lo, hi;
    #pragma unroll
    for (int k = 0; k < 8; ++k){
      float v = (i==0) ? vals[k].x : (i==1) ? vals[k].y : (i==2) ? vals[k].z : vals[k].w;
      lo[k] = f2bf(v * scl[k] + off[k]);
    }
    #pragma unroll
    for (int k = 0; k < 8; ++k){
      float v = (i==0) ? vals[k+8].x : (i==1) ? vals[k+8].y : (i==2) ? vals[k+8].z : vals[k+8].w;
      hi[k] = f2bf(v * scl[k+8] + off[k+8]);
    }
    *reinterpret_cast<s16x8*>(obase + (size_t)i*CC)     = lo;
    *reinterpret_cast<s16x8*>(obase + (size_t)i*CC + 8) = hi;
  }
}

// ---------------- GEMM: Y[o][n] = sum_c W[o][c] * Bmat[n][c] ----------------
// MODE 0: z=0 -> q_t (b,h,n,c)*0.125*log2e; z=1 -> k_t (b,h,n,c); z=2 -> v (b,c,n)
// MODE 1: out f32 (b,c,n) = acc + bias + residual
template<int MODE>
__global__ __launch_bounds__(256) void gemm_kernel(
    const short* __restrict__ Wb, const short* __restrict__ Bmat,
    const float* __restrict__ bias0, const float* __restrict__ bias1, const float* __restrict__ bias2,
    const float* __restrict__ resid,
    short* __restrict__ qt, short* __restrict__ kt2, short* __restrict__ vo,
    float* __restrict__ outp)
{
  const int tile = blockIdx.x;
  const int batch = blockIdx.y;
  const int z = blockIdx.z;
  const int mt = tile >> 3, nt = tile & 7;
  const int tid = threadIdx.x;
  const int lane = tid & 63, wid = tid >> 6;
  const int wm = wid >> 1, wn = wid & 1;

  __shared__ short As[128*64];
  __shared__ short Bs[128*64];

  const short* Wz = Wb + (size_t)(MODE == 0 ? z : 3) * 262144;
  const short* Brow = Bmat + ((size_t)batch*NN + nt*128)*CC;

  const f32x4 fzero = {0.f, 0.f, 0.f, 0.f};
  f32x4 acc[4][4];
  #pragma unroll
  for (int i = 0; i < 4; ++i)
  #pragma unroll
  for (int j = 0; j < 4; ++j)
    acc[i][j] = fzero;

  for (int kk = 0; kk < 8; ++kk){
    __syncthreads();
    #pragma unroll
    for (int j = 0; j < 4; ++j){
      const int id = tid + 256*j;
      const int row = id >> 3, ch = id & 7;
      const int gch = ch ^ (row & 7);
      gload16(Wz   + (size_t)(mt*128 + row)*CC + kk*64 + gch*8, As + (wid*64 + 256*j)*8);
      gload16(Brow + (size_t)row*CC          + kk*64 + gch*8, Bs + (wid*64 + 256*j)*8);
    }
    __syncthreads();
    #pragma unroll
    for (int ks = 0; ks < 2; ++ks){
      s16x8 a[4], b[4];
      #pragma unroll
      for (int mi = 0; mi < 4; ++mi){
        const int row = wm*64 + mi*16 + (lane & 15);
        const int ch = (ks*4 + (lane >> 4)) ^ (row & 7);
        a[mi] = *reinterpret_cast<const s16x8*>(&As[row*64 + ch*8]);
      }
      #pragma unroll
      for (int ni = 0; ni < 4; ++ni){
        const int row = wn*64 + ni*16 + (lane & 15);
        const int ch = (ks*4 + (lane >> 4)) ^ (row & 7);
        b[ni] = *reinterpret_cast<const s16x8*>(&Bs[row*64 + ch*8]);
      }
      #pragma unroll
      for (int mi = 0; mi < 4; ++mi)
      #pragma unroll
      for (int ni = 0; ni < 4; ++ni)
        acc[mi][ni] = __builtin_amdgcn_mfma_f32_16x16x32_bf16(a[mi], b[ni], acc[mi][ni], 0, 0, 0);
    }
  }

  const int obase = mt*128 + wm*64;
  const int nbase = nt*128 + wn*64;
  if (MODE == 0){
    if (z < 2){
      const float* bias = (z == 0) ? bias0 : bias1;
      short* dst = (z == 0) ? qt : kt2;
      const float qs = (z == 0) ? 0.125f * 1.44269504f : 1.0f;   // fold log2(e) into q
      const int head = mt*2 + wm;
      const size_t hb = ((size_t)batch*NH + head)*NN;
      #pragma unroll
      for (int mi = 0; mi < 4; ++mi){
        float bv4[4];
        #pragma unroll
        for (int r = 0; r < 4; ++r) bv4[r] = bias[obase + mi*16 + (lane>>4)*4 + r];
        const int c0 = mi*16 + (lane>>4)*4;
        #pragma unroll
        for (int ni = 0; ni < 4; ++ni){
          const int n = nbase + ni*16 + (lane & 15);
          s16x4 pk;
          #pragma unroll
          for (int r = 0; r < 4; ++r) pk[r] = f2bf((acc[mi][ni][r] + bv4[r]) * qs);
          *reinterpret_cast<s16x4*>(dst + (hb + n)*HD + c0) = pk;
        }
      }
    } else {
      #pragma unroll
      for (int mi = 0; mi < 4; ++mi){
        float bv4[4];
        #pragma unroll
        for (int r = 0; r < 4; ++r) bv4[r] = bias2[obase + mi*16 + (lane>>4)*4 + r];
        #pragma unroll
        for (int ni = 0; ni < 4; ++ni){
          const int n = nbase + ni*16 + (lane & 15);
          #pragma unroll
          for (int r = 0; r < 4; ++r){
            const int o = obase + mi*16 + (lane>>4)*4 + r;
            vo[((size_t)batch*CC + o)*NN + n] = f2bf(acc[mi][ni][r] + bv4[r]);
          }
        }
      }
    }
  } else {
    #pragma unroll
    for (int mi = 0; mi < 4; ++mi){
      float bv4[4];
      #pragma unroll
      for (int r = 0; r < 4; ++r) bv4[r] = bias0[obase + mi*16 + (lane>>4)*4 + r];
      #pragma unroll
      for (int ni = 0; ni < 4; ++ni){
        const int n = nbase + ni*16 + (lane & 15);
        #pragma unroll
        for (int r = 0; r < 4; ++r){
          const int o = obase + mi*16 + (lane>>4)*4 + r;
          const size_t idx = ((size_t)batch*CC + o)*NN + n;
          outp[idx] = acc[mi][ni][r] + bv4[r] + resid[idx];
        }
      }
    }
  }
}

// ---------------- attention: swapped-QK^T 32x32, lane-local softmax, no LDS ----------------
// grid 512: each XCD owns 8 (b,h) pairs (KV 2MB -> L2-resident).
// wave = 32 queries; iter = 64 keys; S^T = mfma(K, Q): col=lane&31=query (lane-local softmax).
__global__ __launch_bounds__(256, 2) void attn_kernel(
    const short* __restrict__ qp, const short* __restrict__ kp, const short* __restrict__ vp,
    short* __restrict__ ot)
{
  const int bid = blockIdx.x;
  const int xcd = bid & 7, slot = bid >> 3;
  const int bh  = xcd*8 + (slot & 7);          // 8 bh per XCD
  const int qti = slot >> 3;                   // 0..7
  const int b = bh >> 3, head = bh & 7;
  const int tid = threadIdx.x, lane = tid & 63, wid = tid >> 6;
  const int col = lane & 31, hi = lane >> 5;

  const short* Qb = qp + (size_t)bh*NN*HD;
  const short* Kb = kp + (size_t)bh*NN*HD;
  const short* Vb = vp + ((size_t)b*CC + head*HD)*NN;

  const int q0 = qti*128 + wid*32;

  // Q B-frags: col=query, k-channel = ks*16 + hi*8 + j
  s16x8 qf[4];
  #pragma unroll
  for (int ks = 0; ks < 4; ++ks)
    qf[ks] = *reinterpret_cast<const s16x8*>(Qb + (size_t)(q0 + col)*HD + ks*16 + hi*8);

  f32x16 of0, of1;
  #pragma unroll
  for (int r = 0; r < 16; ++r){ of0[r] = 0.f; of1[r] = 0.f; }
  float m = -1e30f, l = 0.f;

  auto kload = [&](int it, s16x8 (&kf)[2][4]){
    const short* kb0 = Kb + (size_t)(it*64 + col)*HD + hi*8;
    #pragma unroll
    for (int t = 0; t < 2; ++t)
      #pragma unroll
      for (int ks = 0; ks < 4; ++ks)
        kf[t][ks] = *reinterpret_cast<const s16x8*>(kb0 + t*32*HD + ks*16);
  };

  // pack one 32-key tile of P (f32x16 per lane) into two B-frag s16x8 (keys 0..15, 16..31)
  auto pack = [&](f32x16& sv, s16x8& p0, s16x8& p1){
    union { unsigned u[4]; s16x8 v; } w0, w1;
    {
      unsigned a = cvtpk(sv[0], sv[1]);
      unsigned c = cvtpk(sv[4], sv[5]);
      auto r = __builtin_amdgcn_permlane32_swap(a, c, false, false);
      w0.u[0] = r[0]; w0.u[2] = r[1];
      a = cvtpk(sv[2], sv[3]);
      c = cvtpk(sv[6], sv[7]);
      r = __builtin_amdgcn_permlane32_swap(a, c, false, false);
      w0.u[1] = r[0]; w0.u[3] = r[1];
    }
    {
      unsigned a = cvtpk(sv[8], sv[9]);
      unsigned c = cvtpk(sv[12], sv[13]);
      auto r = __builtin_amdgcn_permlane32_swap(a, c, false, false);
      w1.u[0] = r[0]; w1.u[2] = r[1];
      a = cvtpk(sv[10], sv[11]);
      c = cvtpk(sv[14], sv[15]);
      r = __builtin_amdgcn_permlane32_swap(a, c, false, false);
      w1.u[1] = r[0]; w1.u[3] = r[1];
    }
    p0 = w0.v; p1 = w1.v;
  };

  auto body = [&](int it, s16x8 (&kf)[2][4], s16x8 (&kfn)[2][4]){
    const int m0 = it*64;
    // V A-frags (needed only at PV — issue early, latency hides under QK^T+softmax)
    s16x8 vf[2][4];
    const short* vb0 = Vb + (size_t)col*NN + m0 + hi*8;
    #pragma unroll
    for (int ci = 0; ci < 2; ++ci)
      #pragma unroll
      for (int s = 0; s < 4; ++s)
        vf[ci][s] = *reinterpret_cast<const s16x8*>(vb0 + (size_t)ci*32*NN + s*16);
    // QK^T (scores already in log2 domain via q pre-scale)
    f32x16 s0, s1;
    #pragma unroll
    for (int r = 0; r < 16; ++r){ s0[r] = 0.f; s1[r] = 0.f; }
    #pragma unroll
    for (int ks = 0; ks < 4; ++ks){
      s0 = __builtin_amdgcn_mfma_f32_32x32x16_bf16(kf[0][ks], qf[ks], s0, 0, 0, 0);
      s1 = __builtin_amdgcn_mfma_f32_32x32x16_bf16(kf[1][ks], qf[ks], s1, 0, 0, 0);
    }
    // prefetch next iteration's K
    if (it < 15) kload(it + 1, kfn);
    // lane-local online softmax (lane owns query col; rows split across hi-halves)
    float tm = s0[0];
    #pragma unroll
    for (int r = 1; r < 16; ++r) tm = fmaxf(tm, s0[r]);
    #pragma unroll
    for (int r = 0; r < 16; ++r) tm = fmaxf(tm, s1[r]);
    tm = fmaxf(tm, __shfl_xor(tm, 32));
    const float mn = fmaxf(m, tm);
    const float sc = __builtin_amdgcn_exp2f(m - mn);
    m = mn;
    float rs = 0.f;
    #pragma unroll
    for (int r = 0; r < 16; ++r){ s0[r] = __builtin_amdgcn_exp2f(s0[r] - mn); rs += s0[r]; }
    #pragma unroll
    for (int r = 0; r < 16; ++r){ s1[r] = __builtin_amdgcn_exp2f(s1[r] - mn); rs += s1[r]; }
    rs += __shfl_xor(rs, 32);
    l = l*sc + rs;
    #pragma unroll
    for (int r = 0; r < 16; ++r){ of0[r] *= sc; of1[r] *= sc; }
    // P -> bf16 B-frags in-register (cvt_pk + permlane32_swap)
    s16x8 pf[4];
    pack(s0, pf[0], pf[1]);
    pack(s1, pf[2], pf[3]);
    // O += V * P
    #pragma unroll
    for (int s = 0; s < 4; ++s){
      of0 = __builtin_amdgcn_mfma_f32_32x32x16_bf16(vf[0][s], pf[s], of0, 0, 0, 0);
      of1 = __builtin_amdgcn_mfma_f32_32x32x16_bf16(vf[1][s], pf[s], of1, 0, 0, 0);
    }
  };

  s16x8 kfA[2][4], kfB[2][4];
  kload(0, kfA);
  #pragma unroll 1
  for (int ii = 0; ii < 8; ++ii){
    body(2*ii,     kfA, kfB);
    body(2*ii + 1, kfB, kfA);
  }

  // normalize + store (b, n, c): O rows c = ci*32 + rq*8 + hi*4 + r, col = query
  const float invl = 1.f / l;
  const int n = q0 + col;
  short* ob = ot + ((size_t)b*NN + n)*CC + head*HD + hi*4;
  #pragma unroll
  for (int rq = 0; rq < 4; ++rq){
    s16x4 pk;
    #pragma unroll
    for (int r = 0; r < 4; ++r) pk[r] = f2bf(of0[rq*4 + r] * invl);
    *reinterpret_cast<s16x4*>(ob + rq*8) = pk;
    #pragma unroll
    for (int r = 0; r < 4; ++r) pk[r] = f2bf(of1[rq*4 + r] * invl);
    *reinterpret_cast<s16x4*>(ob + 32 + rq*8) = pk;
  }
}

extern "C" void kernel_launch(void* const* d_in, const int* in_sizes, int n_in,
                              void* d_out, int out_size, void* d_ws, size_t ws_size,
                              hipStream_t stream) {
  const float* x   = (const float*)d_in[0];
  const float* gsc = (const float*)d_in[1];
  const float* gbi = (const float*)d_in[2];
  const float* wq  = (const float*)d_in[3];
  const float* bq  = (const float*)d_in[4];
  const float* wk  = (const float*)d_in[5];
  const float* bk  = (const float*)d_in[6];
  const float* wv  = (const float*)d_in[7];
  const float* bv  = (const float*)d_in[8];
  const float* wp  = (const float*)d_in[9];
  const float* bp  = (const float*)d_in[10];
  float* out = (float*)d_out;

  char* ws = (char*)d_ws;
  short* wbf = (short*)(ws);                 // 2 MiB: wq,wk,wv,wp bf16
  short* xnt = (short*)(ws + (2u<<20));      // 8 MiB: (b,n,c) bf16
  short* qt  = (short*)(ws + (10u<<20));     // 8 MiB: (b,h,n,c) bf16, pre-scaled by 0.125*log2e
  short* kt  = (short*)(ws + (18u<<20));     // 8 MiB: (b,h,n,c) bf16
  short* v   = (short*)(ws + (26u<<20));     // 8 MiB: (b,c,n) bf16
  short* aot = (short*)(ws + (34u<<20));     // 8 MiB: (b,n,c) bf16

  wcvt<<<1024, 256, 0, stream>>>(wq, wk, wv, wp, wbf);
  gn_kernel<<<256, 256, 0, stream>>>(x, gsc, gbi, xnt);
  gemm_kernel<0><<<dim3(32, 8, 3), 256, 0, stream>>>(wbf, xnt, bq, bk, bv, nullptr,
                                                     qt, kt, v, nullptr);
  attn_kernel<<<dim3(512), 256, 0, stream>>>(qt, kt, v, aot);
  gemm_kernel<1><<<dim3(32, 8, 1), 256, 0, stream>>>(wbf, aot, bp, nullptr, nullptr, x,
                                                     nullptr, nullptr, nullptr, out);
}